// Round 13
// baseline (27499.652 us; speedup 1.0000x reference)
//
#include <hip/hip_runtime.h>

// ---------------------------------------------------------------------------
// LayerNorm-LSTM (depth=2) + FC, MI355X. Split-bf16 (hi/lo) 3-term MFMA.
// Round 13: R12 with summer phases deleted (5 sync hops -> 3). Consumers
// self-reduce the overwrite-only partial buffers via ALD64 (L3). Phases:
//   A: hh MFMA + strip(LDS) + LN1 partial stores  -> signal cA
//   C: self-reduce part1 -> LN1 + gates + cell + part2 stores -> signal cC
//   E: self-reduce part2 -> cell-LN + h(slots) + Y -> signal cE
// 33 span launches x 16 steps, Whh hi+lo resident in 128KB LDS.
// ---------------------------------------------------------------------------

typedef __attribute__((ext_vector_type(8))) short short8;
typedef __attribute__((ext_vector_type(8))) __bf16 bf16x8;
typedef __attribute__((ext_vector_type(4))) float f32x4;
typedef __attribute__((ext_vector_type(4))) unsigned short us4;
typedef unsigned long long u64;

#define B_ 64
#define T_ 512
#define D_ 1024
#define H_ 1024
#define FH_ 4096
#define LAG_ 16
#define NSPAN 16
#define SPANS 33               // 33*16 = 528 = T + LAG
#define RCH_ (B_ * 16)

#define SMEM_WHH 131072
#define SMEM_STRIP 8448                           // ldshh [64][33] f32
#define SMEM_TOTAL (SMEM_WHH + SMEM_STRIP + 1024) // + statsL [256] f32

typedef const __attribute__((address_space(1))) unsigned int* gas_ptr;
typedef __attribute__((address_space(3))) unsigned int* las_ptr;
#define GLOAD_LDS16(g, l) \
  __builtin_amdgcn_global_load_lds((gas_ptr)(g), (las_ptr)(l), 16, 0, 0)

#define ALD(p)    __hip_atomic_load((p), __ATOMIC_RELAXED, __HIP_MEMORY_SCOPE_AGENT)
#define ALD64(p)  __hip_atomic_load((p), __ATOMIC_RELAXED, __HIP_MEMORY_SCOPE_AGENT)
#define AST(p, v) __hip_atomic_store((p), (v), __ATOMIC_RELAXED, __HIP_MEMORY_SCOPE_AGENT)

static __device__ __forceinline__ unsigned short f2bf(float f) {
  unsigned int u = __builtin_bit_cast(unsigned int, f);
  u += 0x7FFFu + ((u >> 16) & 1u);   // round-to-nearest-even
  return (unsigned short)(u >> 16);
}
static __device__ __forceinline__ float bf2f(unsigned short u) {
  unsigned int x = ((unsigned int)u) << 16;
  return __builtin_bit_cast(float, x);
}

// ---------------- split-cast fp32 -> (hi, lo) bf16 ----------------
__global__ void cast_split_k(const float4* __restrict__ in,
                             us4* __restrict__ hi, us4* __restrict__ lo, int n4) {
  int i = blockIdx.x * 256 + threadIdx.x;
  if (i < n4) {
    float4 v = in[i];
    us4 h, l;
    h[0] = f2bf(v.x); l[0] = f2bf(v.x - bf2f(h[0]));
    h[1] = f2bf(v.y); l[1] = f2bf(v.y - bf2f(h[1]));
    h[2] = f2bf(v.z); l[2] = f2bf(v.z - bf2f(h[2]));
    h[3] = f2bf(v.w); l[3] = f2bf(v.w - bf2f(h[3]));
    hi[i] = h; lo[i] = l;
  }
}

// ------ transpose-split input [B][T][D] f32 -> [T][B][D] (hi, lo) bf16 -----
__global__ void transpose_split_k(const float4* __restrict__ x,
                                  us4* __restrict__ hi, us4* __restrict__ lo) {
  int i = blockIdx.x * 256 + threadIdx.x;
  int d4  = i & 255;
  int rem = i >> 8;
  int b = rem & 63;
  int t = rem >> 6;
  float4 v = x[((size_t)(b * T_ + t) << 8) + d4];
  us4 h, l;
  h[0] = f2bf(v.x); l[0] = f2bf(v.x - bf2f(h[0]));
  h[1] = f2bf(v.y); l[1] = f2bf(v.y - bf2f(h[1]));
  h[2] = f2bf(v.z); l[2] = f2bf(v.z - bf2f(h[2]));
  h[3] = f2bf(v.w); l[3] = f2bf(v.w - bf2f(h[3]));
  size_t o = ((size_t)(t * B_ + b) << 8) + d4;
  hi[o] = h; lo[o] = l;
}

// ------ fragment-ordered Whh (hi AND lo), gate-interleaved (R8/R12-proven) --
__global__ void whh_frag3_k(const float* __restrict__ w_hh,
                            unsigned short* __restrict__ frag) {
  int i = blockIdx.x * 256 + threadIdx.x;    // 2,097,152 chunks
  int lane = i & 63;
  int kc   = (i >> 6) & 31;
  int g    = (i >> 11) & 1;
  int sel  = (i >> 12) & 1;
  int j    = (i >> 13) & 127;
  int layer= (i >> 20) & 1;
  int fc = lane & 15;
  int gc = (g * 2 + (fc >> 3)) * 1024 + j * 8 + (fc & 7);
  int k0 = kc * 32 + (lane >> 4) * 8;
  const float* src = w_hh + ((size_t)layer * FH_ + gc) * 1024 + k0;
  short8 o;
#pragma unroll
  for (int e = 0; e < 8; ++e) {
    float v = src[e];
    unsigned short h = f2bf(v);
    o[e] = sel ? (short)f2bf(v - bf2f(h)) : (short)h;
  }
  *(short8*)(frag + (size_t)i * 8) = o;
}

// ---------------- 3-term split-bf16 GEMM (chunk projections + FC) ----------
template <int FCMODE>
__global__ __launch_bounds__(256) void gemm3_k(
    const unsigned short* __restrict__ Ahi, const unsigned short* __restrict__ Alo,
    const unsigned short* __restrict__ Whi, const unsigned short* __restrict__ Wlo,
    const float* __restrict__ bias, float* __restrict__ out, int K, int N) {
  __shared__ unsigned short lAh[128 * 40];
  __shared__ unsigned short lAl[128 * 40];
  __shared__ unsigned short lWh[128 * 40];
  __shared__ unsigned short lWl[128 * 40];
  int tid = threadIdx.x;
  int l = tid & 63, w = tid >> 6;
  int r0 = blockIdx.y * 128, c0 = blockIdx.x * 128;
  int wr = (w >> 1) * 64, wc = (w & 1) * 64;
  int lr = l & 15, lk = (l >> 4) * 8;
  f32x4 acc[4][4] = {};
  int srow = tid >> 2;
  int scc  = (tid & 3) * 8;

  for (int kt = 0; kt < K; kt += 32) {
#pragma unroll
    for (int i = 0; i < 2; ++i) {
      int row = srow + i * 64;
      size_t aoff = (size_t)(r0 + row) * K + kt + scc;
      size_t woff = (size_t)(c0 + row) * K + kt + scc;
      *(short8*)&lAh[row * 40 + scc] = *(const short8*)(Ahi + aoff);
      *(short8*)&lAl[row * 40 + scc] = *(const short8*)(Alo + aoff);
      *(short8*)&lWh[row * 40 + scc] = *(const short8*)(Whi + woff);
      *(short8*)&lWl[row * 40 + scc] = *(const short8*)(Wlo + woff);
    }
    __syncthreads();
    bf16x8 ah[4], al[4], bh[4], bl[4];
#pragma unroll
    for (int mi = 0; mi < 4; ++mi) {
      ah[mi] = *(bf16x8*)&lAh[(wr + mi * 16 + lr) * 40 + lk];
      al[mi] = *(bf16x8*)&lAl[(wr + mi * 16 + lr) * 40 + lk];
    }
#pragma unroll
    for (int ni = 0; ni < 4; ++ni) {
      bh[ni] = *(bf16x8*)&lWh[(wc + ni * 16 + lr) * 40 + lk];
      bl[ni] = *(bf16x8*)&lWl[(wc + ni * 16 + lr) * 40 + lk];
    }
#pragma unroll
    for (int mi = 0; mi < 4; ++mi)
#pragma unroll
      for (int ni = 0; ni < 4; ++ni) {
        acc[mi][ni] = __builtin_amdgcn_mfma_f32_16x16x32_bf16(ah[mi], bh[ni], acc[mi][ni], 0, 0, 0);
        acc[mi][ni] = __builtin_amdgcn_mfma_f32_16x16x32_bf16(ah[mi], bl[ni], acc[mi][ni], 0, 0, 0);
        acc[mi][ni] = __builtin_amdgcn_mfma_f32_16x16x32_bf16(al[mi], bh[ni], acc[mi][ni], 0, 0, 0);
      }
    __syncthreads();
  }

#pragma unroll
  for (int mi = 0; mi < 4; ++mi)
#pragma unroll
    for (int ni = 0; ni < 4; ++ni)
#pragma unroll
      for (int reg = 0; reg < 4; ++reg) {
        int r = r0 + wr + mi * 16 + (l >> 4) * 4 + reg;
        int c = c0 + wc + ni * 16 + lr;
        float v = acc[mi][ni][reg] + bias[c];
        if (FCMODE) {
          int b = r & 63, t = r >> 6;
          out[((size_t)b * T_ + t) * (size_t)N + c] = v;
        } else {
          out[(size_t)r * N + c] = v;
        }
      }
}

// ---------------- span kernel ----------------
struct SpanP {
  const unsigned short* whhF;
  const float *P0, *P1;
  unsigned short *hpHi, *hpLo;     // [16 slot][2 layer][64][1024]
  unsigned short *XYhi, *XYlo;
  float* cst;
  const float *bhh, *gih, *beih, *ghh, *behh, *gho, *beho;
  float *part1, *part2;            // [2][64][4][128] / [2][64][2][128]
  unsigned *cnt;                   // 3 sets x [2 layer][8 sub x 16-pad]
  int s0;
};

// sub-counter sets (each [2][8], padded stride 16 u32 = 64B per sub)
#define CSET(set, layer) (p.cnt + ((set) * 2 + (layer)) * 128)

// wave0-only poll of 8 padded sub-counters; other waves park at barrier.
static __device__ __forceinline__ void waitc(const unsigned* c, unsigned tgt) {
  if (threadIdx.x < 64) {
    int l = threadIdx.x;
    for (;;) {
      unsigned v = 0xffffffffu;
      if (l < 8) v = ALD(c + l * 16);
#pragma unroll
      for (int o = 4; o; o >>= 1) {
        unsigned u = (unsigned)__shfl_xor((int)v, o);
        v = v < u ? v : u;
      }
      v = (unsigned)__shfl((int)v, 0);
      if (v >= tgt) break;
      __builtin_amdgcn_s_sleep(1);
    }
  }
  __syncthreads();
}

__global__ __launch_bounds__(512) void span_k(SpanP p) {
  extern __shared__ char smem[];
  unsigned short* wl = (unsigned short*)smem;            // 128KB Whh frags
  float* ldshh = (float*)(smem + SMEM_WHH);              // [64][33]
  float* statsL = (float*)(smem + SMEM_WHH + SMEM_STRIP);// [256]

  const int tid = threadIdx.x;
  const int blk = blockIdx.x;
  const int layer = blk >> 7;
  const int j = blk & 127;
  const int w = tid >> 6, l = tid & 63;
  const int lr = l & 15, lq = l >> 4;
  const int row = tid >> 3, c8 = tid & 7;
  const int hcol = j * 8 + c8;
  const int subj = j & 7;

  // ---- stage Whh hi+lo frag slice (once per span) ----
  {
    const unsigned short* gsrc = p.whhF + ((size_t)blk << 16);
#pragma unroll
    for (int r = 0; r < 16; ++r) {
      int c = r * 512 + tid;
      GLOAD_LDS16(gsrc + (size_t)c * 8, wl + (size_t)c * 8);
    }
  }

  // ---- cache per-thread params for the whole span ----
  float gihv[4], beihv[4], ghhv[4], behhv[4];
#pragma unroll
  for (int q = 0; q < 4; ++q) {
    int gc = layer * FH_ + q * 1024 + hcol;
    gihv[q] = p.gih[gc]; beihv[q] = p.beih[gc];
    ghhv[q] = p.ghh[gc]; behhv[q] = p.behh[gc];
  }
  float ghov  = p.gho[layer * H_ + hcol];
  float behov = p.beho[layer * H_ + hcol];
  // strip-write bias for this thread's (wave colgroup, fragment col)
  const int gch = w & 1;
  const int q4 = gch * 2 + (lr >> 3);
  const float bhhv = p.bhh[layer * FH_ + q4 * 1024 + j * 8 + (lr & 7)];
  float creg = p.cst[((size_t)(layer * B_ + row)) * H_ + hcol];

  __syncthreads();   // staging drained (vmcnt 0)

  for (int sl = 0; sl < NSPAN; ++sl) {
    const int s = p.s0 + sl;
    const unsigned g = (unsigned)(s + 1);
    const int t0 = layer ? (s - LAG_) : s;
    const bool active = (t0 >= 0) && (t0 < T_);
    const int slotp = (sl - 1) & 15;
    const int slot = sl;

    // ============ phase A: hh MFMA + strip + LN1 partial stores ============
    waitc(CSET(2, layer), 16u * (g - 1));
    float ih[4] = {0, 0, 0, 0}, hh[4] = {0, 0, 0, 0};
    if (active) {
      const float* Pb = layer ? p.P1 : p.P0;
#pragma unroll
      for (int q = 0; q < 4; ++q)
        ih[q] = Pb[((size_t)(sl * B_ + row)) * FH_ + q * 1024 + hcol];

      const int rf = w >> 1;
      const int rowbase = rf * 16;
      const unsigned short* hHb = p.hpHi + ((size_t)(slotp * 2 + layer)) * 65536;
      const unsigned short* hLb = p.hpLo + ((size_t)(slotp * 2 + layer)) * 65536;
      f32x4 acc = {};
#pragma unroll 8
      for (int kc = 0; kc < 32; ++kc) {
        int k = kc * 32 + lq * 8;
        bf16x8 ah = __builtin_bit_cast(bf16x8, *(const short8*)(hHb + (rowbase + lr) * 1024 + k));
        bf16x8 al = __builtin_bit_cast(bf16x8, *(const short8*)(hLb + (rowbase + lr) * 1024 + k));
        bf16x8 bh = __builtin_bit_cast(bf16x8, *(const short8*)&wl[(size_t)(gch * 2048 + kc * 64 + l) * 8]);
        bf16x8 bl = __builtin_bit_cast(bf16x8, *(const short8*)&wl[(size_t)(4096 + gch * 2048 + kc * 64 + l) * 8]);
        acc = __builtin_amdgcn_mfma_f32_16x16x32_bf16(ah, bh, acc, 0, 0, 0);
        acc = __builtin_amdgcn_mfma_f32_16x16x32_bf16(al, bh, acc, 0, 0, 0);
        acc = __builtin_amdgcn_mfma_f32_16x16x32_bf16(ah, bl, acc, 0, 0, 0);
      }
      int bc = q4 * 8 + (lr & 7);
#pragma unroll
      for (int reg = 0; reg < 4; ++reg)
        ldshh[(rowbase + lq * 4 + reg) * 33 + bc] = acc[reg] + bhhv;
    }
    __syncthreads();
    if (active) {
      float s1 = 0, q1 = 0, s2 = 0, q2 = 0;
#pragma unroll
      for (int q = 0; q < 4; ++q) {
        float a = ih[q];
        float b = ldshh[row * 33 + q * 8 + c8];
        hh[q] = b;
        s1 += a; q1 += a * a; s2 += b; q2 += b * b;
      }
#pragma unroll
      for (int o = 1; o < 8; o <<= 1) {
        s1 += __shfl_xor(s1, o); q1 += __shfl_xor(q1, o);
        s2 += __shfl_xor(s2, o); q2 += __shfl_xor(q2, o);
      }
      if (c8 == 0) {
        float* pb = p.part1 + ((size_t)(layer * 64 + row) * 4) * 128 + j;
        AST(pb + 0 * 128, s1); AST(pb + 1 * 128, q1);
        AST(pb + 2 * 128, s2); AST(pb + 3 * 128, q2);
      }
    }
    __syncthreads();
    if (tid == 0) atomicAdd(CSET(0, layer) + subj * 16, 1u);

    // ============ phase C: self-reduce LN1 + gates + cell + part2 stores ===
    waitc(CSET(0, layer), 16u * g);
    if (active) {
      int pp = tid >> 1;                 // 0..255 = row*4 + st
      const u64* src = (const u64*)(p.part1 +
          (((size_t)layer * 64 + (pp >> 2)) * 4 + (pp & 3)) * 128) + (tid & 1) * 32;
      float ssum = 0.0f;
#pragma unroll
      for (int i = 0; i < 32; ++i) {
        u64 v = ALD64(src + i);
        ssum += __builtin_bit_cast(float, (unsigned)v)
              + __builtin_bit_cast(float, (unsigned)(v >> 32));
      }
      ssum += __shfl_xor(ssum, 1);
      if ((tid & 1) == 0) statsL[pp] = ssum;
    }
    __syncthreads();
    float ogate = 0.0f;
    if (active) {
      float S1 = statsL[row * 4 + 0], Q1 = statsL[row * 4 + 1];
      float S2 = statsL[row * 4 + 2], Q2 = statsL[row * 4 + 3];
      const float inv4h = 1.0f / 4096.0f;
      float m1 = S1 * inv4h, m2 = S2 * inv4h;
      float i1 = rsqrtf(Q1 * inv4h - m1 * m1 + 1e-5f);
      float i2 = rsqrtf(Q2 * inv4h - m2 * m2 + 1e-5f);
      float pre[4];
#pragma unroll
      for (int q = 0; q < 4; ++q)
        pre[q] = gihv[q] * (ih[q] - m1) * i1 + beihv[q]
               + ghhv[q] * (hh[q] - m2) * i2 + behhv[q];
      float iG = 1.0f / (1.0f + __expf(-pre[0]));
      float fG = 1.0f / (1.0f + __expf(-pre[1]));
      float oG = 1.0f / (1.0f + __expf(-pre[2]));
      float gG = tanhf(pre[3]);
      creg = fG * creg + iG * gG;
      ogate = oG;
      float sc = creg, sq = creg * creg;
#pragma unroll
      for (int o = 1; o < 8; o <<= 1) { sc += __shfl_xor(sc, o); sq += __shfl_xor(sq, o); }
      if (c8 == 0) {
        float* pb = p.part2 + ((size_t)(layer * 64 + row) * 2) * 128 + j;
        AST(pb + 0 * 128, sc); AST(pb + 1 * 128, sq);
      }
    }
    __syncthreads();
    if (tid == 0) atomicAdd(CSET(1, layer) + subj * 16, 1u);

    // ============ phase E: self-reduce cell stats + cell-LN + h + Y ========
    waitc(CSET(1, layer), 16u * g);
    if (active) {
      int pp = tid >> 2;                 // 0..127 = row*2 + st
      const u64* src = (const u64*)(p.part2 +
          (((size_t)layer * 64 + (pp >> 1)) * 2 + (pp & 1)) * 128) + (tid & 3) * 16;
      float ssum = 0.0f;
#pragma unroll
      for (int i = 0; i < 16; ++i) {
        u64 v = ALD64(src + i);
        ssum += __builtin_bit_cast(float, (unsigned)v)
              + __builtin_bit_cast(float, (unsigned)(v >> 32));
      }
      ssum += __shfl_xor(ssum, 1);
      ssum += __shfl_xor(ssum, 2);
      if ((tid & 3) == 0) statsL[pp] = ssum;
    }
    __syncthreads();
    if (active) {
      float S3 = statsL[row * 2 + 0], Q3 = statsL[row * 2 + 1];
      const float invh = 1.0f / 1024.0f;
      float m3 = S3 * invh;
      float i3 = rsqrtf(Q3 * invh - m3 * m3 + 1e-5f);
      float hy = ogate * tanhf((creg - m3) * i3 * ghov + behov);
      unsigned hv = f2bf(hy);
      unsigned lv = f2bf(hy - bf2f(hv));
      unsigned hv2 = (unsigned)__shfl_down((int)hv, 1);
      unsigned lv2 = (unsigned)__shfl_down((int)lv, 1);
      if ((c8 & 1) == 0) {
        size_t i32 = (((size_t)(slot * 2 + layer) * 64 + row) * 1024 + hcol) >> 1;
        AST((unsigned*)p.hpHi + i32, hv | (hv2 << 16));
        AST((unsigned*)p.hpLo + i32, lv | (lv2 << 16));
      }
      size_t yo = ((size_t)t0 * B_ + row) * H_ + hcol;
      p.XYhi[yo] = (unsigned short)hv;
      p.XYlo[yo] = (unsigned short)lv;
    }
    __syncthreads();
    if (tid == 0) atomicAdd(CSET(2, layer) + subj * 16, 1u);
  }

  // ---- span epilogue: persist c-state ----
  p.cst[((size_t)(layer * B_ + row)) * H_ + hcol] = creg;
}

// ---------------------------------------------------------------------------
extern "C" void kernel_launch(void* const* d_in, const int* in_sizes, int n_in,
                              void* d_out, int out_size, void* d_ws, size_t ws_size,
                              hipStream_t stream) {
  const float* x    = (const float*)d_in[0];
  const float* w_ih = (const float*)d_in[1];
  const float* b_ih = (const float*)d_in[2];
  const float* w_hh = (const float*)d_in[3];
  const float* b_hh = (const float*)d_in[4];
  const float* g_ih = (const float*)d_in[5];
  const float* be_ih= (const float*)d_in[6];
  const float* g_hh = (const float*)d_in[7];
  const float* be_hh= (const float*)d_in[8];
  const float* g_ho = (const float*)d_in[9];
  const float* be_ho= (const float*)d_in[10];
  const float* fc_w = (const float*)d_in[11];
  const float* fc_b = (const float*)d_in[12];
  float* out = (float*)d_out;
  (void)ws_size; (void)in_sizes; (void)n_in; (void)out_size;

  // workspace carve-up (~247 MB)
  char* wsb = (char*)d_ws;
  size_t off = 0;
  unsigned short* wihHi  = (unsigned short*)(wsb + off); off += 16777216;
  unsigned short* wihLo  = (unsigned short*)(wsb + off); off += 16777216;
  unsigned short* whhF   = (unsigned short*)(wsb + off); off += 33554432;
  unsigned short* fcHi   = (unsigned short*)(wsb + off); off += 2097152;
  unsigned short* fcLo   = (unsigned short*)(wsb + off); off += 2097152;
  unsigned short* XYhi   = (unsigned short*)(wsb + off); off += 67108864;
  unsigned short* XYlo   = (unsigned short*)(wsb + off); off += 67108864;
  float* P0              = (float*)(wsb + off); off += (size_t)16 * B_ * FH_ * 4;
  float* P1              = (float*)(wsb + off); off += (size_t)16 * B_ * FH_ * 4;
  unsigned short* hpHi   = (unsigned short*)(wsb + off); off += 4194304;  // [16][2][64][1024]
  unsigned short* hpLo   = (unsigned short*)(wsb + off); off += 4194304;
  float* cst             = (float*)(wsb + off); off += 524288;
  float* part1           = (float*)(wsb + off); off += 524288;   // [2][64][4][128]
  float* part2           = (float*)(wsb + off); off += 262144;   // [2][64][2][128]
  unsigned* cnt          = (unsigned*)(wsb + off); off += 3072;  // 3 sets x [2][8x16]

  // --- weight prep ---
  {
    int n4 = 2 * FH_ * D_ / 4;
    cast_split_k<<<(n4 + 255) / 256, 256, 0, stream>>>((const float4*)w_ih, (us4*)wihHi, (us4*)wihLo, n4);
    int nf = H_ * H_ / 4;
    cast_split_k<<<(nf + 255) / 256, 256, 0, stream>>>((const float4*)fc_w, (us4*)fcHi, (us4*)fcLo, nf);
    int nx = T_ * B_ * D_ / 4;
    transpose_split_k<<<nx / 256, 256, 0, stream>>>((const float4*)x, (us4*)XYhi, (us4*)XYlo);
    whh_frag3_k<<<8192, 256, 0, stream>>>(w_hh, whhF);
  }

  // --- state init (graph nodes; re-run each replay) ---
  hipMemsetAsync(hpHi, 0, 8388608, stream);            // hpHi+hpLo contiguous
  hipMemsetAsync(cst, 0, 524288, stream);
  hipMemsetAsync(cnt, 0, 3072, stream);

  hipFuncSetAttribute(reinterpret_cast<const void*>(span_k),
                      hipFuncAttributeMaxDynamicSharedMemorySize, SMEM_TOTAL);

  // --- recurrence: 33 span launches, chunk GEMMs interleaved ---
  SpanP prm;
  prm.whhF = whhF; prm.P0 = P0; prm.P1 = P1;
  prm.hpHi = hpHi; prm.hpLo = hpLo; prm.XYhi = XYhi; prm.XYlo = XYlo;
  prm.cst = cst;
  prm.bhh = b_hh; prm.gih = g_ih; prm.beih = be_ih;
  prm.ghh = g_hh; prm.behh = be_hh; prm.gho = g_ho; prm.beho = be_ho;
  prm.part1 = part1; prm.part2 = part2;
  prm.cnt = cnt;

  for (int c = 0; c < SPANS; ++c) {
    int s = c * NSPAN;
    if (s < T_) {
      gemm3_k<0><<<dim3(FH_ / 128, RCH_ / 128), 256, 0, stream>>>(
          XYhi + (size_t)s * B_ * D_, XYlo + (size_t)s * B_ * D_,
          wihHi, wihLo, b_ih, P0, D_, FH_);
    }
    if (s >= LAG_) {
      gemm3_k<0><<<dim3(FH_ / 128, RCH_ / 128), 256, 0, stream>>>(
          XYhi + (size_t)(s - LAG_) * B_ * D_, XYlo + (size_t)(s - LAG_) * B_ * D_,
          wihHi + (1 << 22), wihLo + (1 << 22), b_ih + FH_, P1, D_, FH_);
    }
    prm.s0 = s;
    span_k<<<256, 512, SMEM_TOTAL, stream>>>(prm);
  }

  // --- final FC: out[b][t][c] = Y1[t*B+b,:]·fc_w[c,:] + fc_b ---
  gemm3_k<1><<<dim3(H_ / 128, (T_ * B_) / 128), 256, 0, stream>>>(
      XYhi, XYlo, fcHi, fcLo, fc_b, out, H_, H_);
}

// Round 14
// 18567.548 us; speedup vs baseline: 1.4811x; 1.4811x over previous
//
#include <hip/hip_runtime.h>

// ---------------------------------------------------------------------------
// LayerNorm-LSTM (depth=2) + FC, MI355X. Split-bf16 (hi/lo) 3-term MFMA.
// Round 14: R13's 3-phase span kernel with the self-reduce on the CACHED
// path: part1/part2 get 16-slot rotation (like h), written with device-scope
// stores, read with plain loads (slot never stale in a reader's L2 within a
// dispatch; kernel boundary invalidates between spans). Phases per step:
//   A: hh MFMA + strip(LDS) + part1[slot] stores -> signal cA
//   C: cached self-reduce part1 -> LN1+gates+cell + part2[slot] -> signal cC
//   E: cached self-reduce part2 -> cell-LN + h(slots) + Y -> signal cE
// ---------------------------------------------------------------------------

typedef __attribute__((ext_vector_type(8))) short short8;
typedef __attribute__((ext_vector_type(8))) __bf16 bf16x8;
typedef __attribute__((ext_vector_type(4))) float f32x4;
typedef __attribute__((ext_vector_type(4))) unsigned short us4;
typedef unsigned long long u64;

#define B_ 64
#define T_ 512
#define D_ 1024
#define H_ 1024
#define FH_ 4096
#define LAG_ 16
#define NSPAN 16
#define SPANS 33               // 33*16 = 528 = T + LAG
#define RCH_ (B_ * 16)

#define SMEM_WHH 131072
#define SMEM_STRIP 8448                           // ldshh [64][33] f32
#define SMEM_TOTAL (SMEM_WHH + SMEM_STRIP + 1024) // + statsL [256] f32

typedef const __attribute__((address_space(1))) unsigned int* gas_ptr;
typedef __attribute__((address_space(3))) unsigned int* las_ptr;
#define GLOAD_LDS16(g, l) \
  __builtin_amdgcn_global_load_lds((gas_ptr)(g), (las_ptr)(l), 16, 0, 0)

#define ALD(p)    __hip_atomic_load((p), __ATOMIC_RELAXED, __HIP_MEMORY_SCOPE_AGENT)
#define AST(p, v) __hip_atomic_store((p), (v), __ATOMIC_RELAXED, __HIP_MEMORY_SCOPE_AGENT)

static __device__ __forceinline__ unsigned short f2bf(float f) {
  unsigned int u = __builtin_bit_cast(unsigned int, f);
  u += 0x7FFFu + ((u >> 16) & 1u);   // round-to-nearest-even
  return (unsigned short)(u >> 16);
}
static __device__ __forceinline__ float bf2f(unsigned short u) {
  unsigned int x = ((unsigned int)u) << 16;
  return __builtin_bit_cast(float, x);
}

// ---------------- split-cast fp32 -> (hi, lo) bf16 ----------------
__global__ void cast_split_k(const float4* __restrict__ in,
                             us4* __restrict__ hi, us4* __restrict__ lo, int n4) {
  int i = blockIdx.x * 256 + threadIdx.x;
  if (i < n4) {
    float4 v = in[i];
    us4 h, l;
    h[0] = f2bf(v.x); l[0] = f2bf(v.x - bf2f(h[0]));
    h[1] = f2bf(v.y); l[1] = f2bf(v.y - bf2f(h[1]));
    h[2] = f2bf(v.z); l[2] = f2bf(v.z - bf2f(h[2]));
    h[3] = f2bf(v.w); l[3] = f2bf(v.w - bf2f(h[3]));
    hi[i] = h; lo[i] = l;
  }
}

// ------ transpose-split input [B][T][D] f32 -> [T][B][D] (hi, lo) bf16 -----
__global__ void transpose_split_k(const float4* __restrict__ x,
                                  us4* __restrict__ hi, us4* __restrict__ lo) {
  int i = blockIdx.x * 256 + threadIdx.x;
  int d4  = i & 255;
  int rem = i >> 8;
  int b = rem & 63;
  int t = rem >> 6;
  float4 v = x[((size_t)(b * T_ + t) << 8) + d4];
  us4 h, l;
  h[0] = f2bf(v.x); l[0] = f2bf(v.x - bf2f(h[0]));
  h[1] = f2bf(v.y); l[1] = f2bf(v.y - bf2f(h[1]));
  h[2] = f2bf(v.z); l[2] = f2bf(v.z - bf2f(h[2]));
  h[3] = f2bf(v.w); l[3] = f2bf(v.w - bf2f(h[3]));
  size_t o = ((size_t)(t * B_ + b) << 8) + d4;
  hi[o] = h; lo[o] = l;
}

// ------ fragment-ordered Whh (hi AND lo), gate-interleaved (R8/R12-proven) --
__global__ void whh_frag3_k(const float* __restrict__ w_hh,
                            unsigned short* __restrict__ frag) {
  int i = blockIdx.x * 256 + threadIdx.x;    // 2,097,152 chunks
  int lane = i & 63;
  int kc   = (i >> 6) & 31;
  int g    = (i >> 11) & 1;
  int sel  = (i >> 12) & 1;
  int j    = (i >> 13) & 127;
  int layer= (i >> 20) & 1;
  int fc = lane & 15;
  int gc = (g * 2 + (fc >> 3)) * 1024 + j * 8 + (fc & 7);
  int k0 = kc * 32 + (lane >> 4) * 8;
  const float* src = w_hh + ((size_t)layer * FH_ + gc) * 1024 + k0;
  short8 o;
#pragma unroll
  for (int e = 0; e < 8; ++e) {
    float v = src[e];
    unsigned short h = f2bf(v);
    o[e] = sel ? (short)f2bf(v - bf2f(h)) : (short)h;
  }
  *(short8*)(frag + (size_t)i * 8) = o;
}

// ---------------- 3-term split-bf16 GEMM (chunk projections + FC) ----------
template <int FCMODE>
__global__ __launch_bounds__(256) void gemm3_k(
    const unsigned short* __restrict__ Ahi, const unsigned short* __restrict__ Alo,
    const unsigned short* __restrict__ Whi, const unsigned short* __restrict__ Wlo,
    const float* __restrict__ bias, float* __restrict__ out, int K, int N) {
  __shared__ unsigned short lAh[128 * 40];
  __shared__ unsigned short lAl[128 * 40];
  __shared__ unsigned short lWh[128 * 40];
  __shared__ unsigned short lWl[128 * 40];
  int tid = threadIdx.x;
  int l = tid & 63, w = tid >> 6;
  int r0 = blockIdx.y * 128, c0 = blockIdx.x * 128;
  int wr = (w >> 1) * 64, wc = (w & 1) * 64;
  int lr = l & 15, lk = (l >> 4) * 8;
  f32x4 acc[4][4] = {};
  int srow = tid >> 2;
  int scc  = (tid & 3) * 8;

  for (int kt = 0; kt < K; kt += 32) {
#pragma unroll
    for (int i = 0; i < 2; ++i) {
      int row = srow + i * 64;
      size_t aoff = (size_t)(r0 + row) * K + kt + scc;
      size_t woff = (size_t)(c0 + row) * K + kt + scc;
      *(short8*)&lAh[row * 40 + scc] = *(const short8*)(Ahi + aoff);
      *(short8*)&lAl[row * 40 + scc] = *(const short8*)(Alo + aoff);
      *(short8*)&lWh[row * 40 + scc] = *(const short8*)(Whi + woff);
      *(short8*)&lWl[row * 40 + scc] = *(const short8*)(Wlo + woff);
    }
    __syncthreads();
    bf16x8 ah[4], al[4], bh[4], bl[4];
#pragma unroll
    for (int mi = 0; mi < 4; ++mi) {
      ah[mi] = *(bf16x8*)&lAh[(wr + mi * 16 + lr) * 40 + lk];
      al[mi] = *(bf16x8*)&lAl[(wr + mi * 16 + lr) * 40 + lk];
    }
#pragma unroll
    for (int ni = 0; ni < 4; ++ni) {
      bh[ni] = *(bf16x8*)&lWh[(wc + ni * 16 + lr) * 40 + lk];
      bl[ni] = *(bf16x8*)&lWl[(wc + ni * 16 + lr) * 40 + lk];
    }
#pragma unroll
    for (int mi = 0; mi < 4; ++mi)
#pragma unroll
      for (int ni = 0; ni < 4; ++ni) {
        acc[mi][ni] = __builtin_amdgcn_mfma_f32_16x16x32_bf16(ah[mi], bh[ni], acc[mi][ni], 0, 0, 0);
        acc[mi][ni] = __builtin_amdgcn_mfma_f32_16x16x32_bf16(ah[mi], bl[ni], acc[mi][ni], 0, 0, 0);
        acc[mi][ni] = __builtin_amdgcn_mfma_f32_16x16x32_bf16(al[mi], bh[ni], acc[mi][ni], 0, 0, 0);
      }
    __syncthreads();
  }

#pragma unroll
  for (int mi = 0; mi < 4; ++mi)
#pragma unroll
    for (int ni = 0; ni < 4; ++ni)
#pragma unroll
      for (int reg = 0; reg < 4; ++reg) {
        int r = r0 + wr + mi * 16 + (l >> 4) * 4 + reg;
        int c = c0 + wc + ni * 16 + lr;
        float v = acc[mi][ni][reg] + bias[c];
        if (FCMODE) {
          int b = r & 63, t = r >> 6;
          out[((size_t)b * T_ + t) * (size_t)N + c] = v;
        } else {
          out[(size_t)r * N + c] = v;
        }
      }
}

// ---------------- span kernel ----------------
struct SpanP {
  const unsigned short* whhF;
  const float *P0, *P1;
  unsigned short *hpHi, *hpLo;     // [16 slot][2 layer][64][1024]
  unsigned short *XYhi, *XYlo;
  float* cst;
  const float *bhh, *gih, *beih, *ghh, *behh, *gho, *beho;
  float *part1, *part2;            // [16][2][64][4][128] / [16][2][64][2][128]
  unsigned *cnt;                   // 3 sets x [2 layer][8 sub x 16-pad]
  int s0;
};

// sub-counter sets (each [2][8], padded stride 16 u32 = 64B per sub)
#define CSET(set, layer) (p.cnt + ((set) * 2 + (layer)) * 128)

// wave0-only poll of 8 padded sub-counters; other waves park at barrier.
static __device__ __forceinline__ void waitc(const unsigned* c, unsigned tgt) {
  if (threadIdx.x < 64) {
    int l = threadIdx.x;
    for (;;) {
      unsigned v = 0xffffffffu;
      if (l < 8) v = ALD(c + l * 16);
#pragma unroll
      for (int o = 4; o; o >>= 1) {
        unsigned u = (unsigned)__shfl_xor((int)v, o);
        v = v < u ? v : u;
      }
      v = (unsigned)__shfl((int)v, 0);
      if (v >= tgt) break;
      __builtin_amdgcn_s_sleep(1);
    }
  }
  __syncthreads();
}

__global__ __launch_bounds__(512) void span_k(SpanP p) {
  extern __shared__ char smem[];
  unsigned short* wl = (unsigned short*)smem;            // 128KB Whh frags
  float* ldshh = (float*)(smem + SMEM_WHH);              // [64][33]
  float* statsL = (float*)(smem + SMEM_WHH + SMEM_STRIP);// [256]

  const int tid = threadIdx.x;
  const int blk = blockIdx.x;
  const int layer = blk >> 7;
  const int j = blk & 127;
  const int w = tid >> 6, l = tid & 63;
  const int lr = l & 15, lq = l >> 4;
  const int row = tid >> 3, c8 = tid & 7;
  const int hcol = j * 8 + c8;
  const int subj = j & 7;

  // ---- stage Whh hi+lo frag slice (once per span) ----
  {
    const unsigned short* gsrc = p.whhF + ((size_t)blk << 16);
#pragma unroll
    for (int r = 0; r < 16; ++r) {
      int c = r * 512 + tid;
      GLOAD_LDS16(gsrc + (size_t)c * 8, wl + (size_t)c * 8);
    }
  }

  // ---- cache per-thread params for the whole span ----
  float gihv[4], beihv[4], ghhv[4], behhv[4];
#pragma unroll
  for (int q = 0; q < 4; ++q) {
    int gc = layer * FH_ + q * 1024 + hcol;
    gihv[q] = p.gih[gc]; beihv[q] = p.beih[gc];
    ghhv[q] = p.ghh[gc]; behhv[q] = p.behh[gc];
  }
  float ghov  = p.gho[layer * H_ + hcol];
  float behov = p.beho[layer * H_ + hcol];
  // strip-write bias for this thread's (wave colgroup, fragment col)
  const int gch = w & 1;
  const int q4 = gch * 2 + (lr >> 3);
  const float bhhv = p.bhh[layer * FH_ + q4 * 1024 + j * 8 + (lr & 7)];
  float creg = p.cst[((size_t)(layer * B_ + row)) * H_ + hcol];

  __syncthreads();   // staging drained (vmcnt 0)

  for (int sl = 0; sl < NSPAN; ++sl) {
    const int s = p.s0 + sl;
    const unsigned g = (unsigned)(s + 1);
    const int t0 = layer ? (s - LAG_) : s;
    const bool active = (t0 >= 0) && (t0 < T_);
    const int slotp = (sl - 1) & 15;
    const int slot = sl;

    // ============ phase A: hh MFMA + strip + part1[slot] stores ============
    waitc(CSET(2, layer), 16u * (g - 1));
    float ih[4] = {0, 0, 0, 0}, hh[4] = {0, 0, 0, 0};
    if (active) {
      const float* Pb = layer ? p.P1 : p.P0;
#pragma unroll
      for (int q = 0; q < 4; ++q)
        ih[q] = Pb[((size_t)(sl * B_ + row)) * FH_ + q * 1024 + hcol];

      const int rf = w >> 1;
      const int rowbase = rf * 16;
      const unsigned short* hHb = p.hpHi + ((size_t)(slotp * 2 + layer)) * 65536;
      const unsigned short* hLb = p.hpLo + ((size_t)(slotp * 2 + layer)) * 65536;
      f32x4 acc = {};
#pragma unroll 8
      for (int kc = 0; kc < 32; ++kc) {
        int k = kc * 32 + lq * 8;
        bf16x8 ah = __builtin_bit_cast(bf16x8, *(const short8*)(hHb + (rowbase + lr) * 1024 + k));
        bf16x8 al = __builtin_bit_cast(bf16x8, *(const short8*)(hLb + (rowbase + lr) * 1024 + k));
        bf16x8 bh = __builtin_bit_cast(bf16x8, *(const short8*)&wl[(size_t)(gch * 2048 + kc * 64 + l) * 8]);
        bf16x8 bl = __builtin_bit_cast(bf16x8, *(const short8*)&wl[(size_t)(4096 + gch * 2048 + kc * 64 + l) * 8]);
        acc = __builtin_amdgcn_mfma_f32_16x16x32_bf16(ah, bh, acc, 0, 0, 0);
        acc = __builtin_amdgcn_mfma_f32_16x16x32_bf16(al, bh, acc, 0, 0, 0);
        acc = __builtin_amdgcn_mfma_f32_16x16x32_bf16(ah, bl, acc, 0, 0, 0);
      }
      int bc = q4 * 8 + (lr & 7);
#pragma unroll
      for (int reg = 0; reg < 4; ++reg)
        ldshh[(rowbase + lq * 4 + reg) * 33 + bc] = acc[reg] + bhhv;
    }
    __syncthreads();
    if (active) {
      float s1 = 0, q1 = 0, s2 = 0, q2 = 0;
#pragma unroll
      for (int q = 0; q < 4; ++q) {
        float a = ih[q];
        float b = ldshh[row * 33 + q * 8 + c8];
        hh[q] = b;
        s1 += a; q1 += a * a; s2 += b; q2 += b * b;
      }
#pragma unroll
      for (int o = 1; o < 8; o <<= 1) {
        s1 += __shfl_xor(s1, o); q1 += __shfl_xor(q1, o);
        s2 += __shfl_xor(s2, o); q2 += __shfl_xor(q2, o);
      }
      if (c8 == 0) {
        float* pb = p.part1 + ((size_t)(slot * 2 + layer) * 256 + row * 4) * 128 + j;
        AST(pb + 0 * 128, s1); AST(pb + 1 * 128, q1);
        AST(pb + 2 * 128, s2); AST(pb + 3 * 128, q2);
      }
    }
    __syncthreads();
    if (tid == 0) atomicAdd(CSET(0, layer) + subj * 16, 1u);

    // ============ phase C: cached self-reduce LN1 + gates + cell ===========
    waitc(CSET(0, layer), 16u * g);
    if (active) {
      int pp = tid >> 1;                 // 0..255 = row*4 + st
      const u64* src = (const u64*)(p.part1 +
          ((size_t)(slot * 2 + layer) * 256 + pp) * 128) + (tid & 1) * 32;
      float ssum = 0.0f;
#pragma unroll
      for (int i = 0; i < 32; ++i) {
        u64 v = src[i];
        ssum += __builtin_bit_cast(float, (unsigned)v)
              + __builtin_bit_cast(float, (unsigned)(v >> 32));
      }
      ssum += __shfl_xor(ssum, 1);
      if ((tid & 1) == 0) statsL[pp] = ssum;
    }
    __syncthreads();
    float ogate = 0.0f;
    if (active) {
      float S1 = statsL[row * 4 + 0], Q1 = statsL[row * 4 + 1];
      float S2 = statsL[row * 4 + 2], Q2 = statsL[row * 4 + 3];
      const float inv4h = 1.0f / 4096.0f;
      float m1 = S1 * inv4h, m2 = S2 * inv4h;
      float i1 = rsqrtf(Q1 * inv4h - m1 * m1 + 1e-5f);
      float i2 = rsqrtf(Q2 * inv4h - m2 * m2 + 1e-5f);
      float pre[4];
#pragma unroll
      for (int q = 0; q < 4; ++q)
        pre[q] = gihv[q] * (ih[q] - m1) * i1 + beihv[q]
               + ghhv[q] * (hh[q] - m2) * i2 + behhv[q];
      float iG = 1.0f / (1.0f + __expf(-pre[0]));
      float fG = 1.0f / (1.0f + __expf(-pre[1]));
      float oG = 1.0f / (1.0f + __expf(-pre[2]));
      float gG = tanhf(pre[3]);
      creg = fG * creg + iG * gG;
      ogate = oG;
      float sc = creg, sq = creg * creg;
#pragma unroll
      for (int o = 1; o < 8; o <<= 1) { sc += __shfl_xor(sc, o); sq += __shfl_xor(sq, o); }
      if (c8 == 0) {
        float* pb = p.part2 + ((size_t)(slot * 2 + layer) * 128 + row * 2) * 128 + j;
        AST(pb + 0 * 128, sc); AST(pb + 1 * 128, sq);
      }
    }
    __syncthreads();
    if (tid == 0) atomicAdd(CSET(1, layer) + subj * 16, 1u);

    // ============ phase E: cached self-reduce cell stats + cell-LN + h + Y =
    waitc(CSET(1, layer), 16u * g);
    if (active) {
      int pp = tid >> 2;                 // 0..127 = row*2 + st
      const u64* src = (const u64*)(p.part2 +
          ((size_t)(slot * 2 + layer) * 128 + pp) * 128) + (tid & 3) * 16;
      float ssum = 0.0f;
#pragma unroll
      for (int i = 0; i < 16; ++i) {
        u64 v = src[i];
        ssum += __builtin_bit_cast(float, (unsigned)v)
              + __builtin_bit_cast(float, (unsigned)(v >> 32));
      }
      ssum += __shfl_xor(ssum, 1);
      ssum += __shfl_xor(ssum, 2);
      if ((tid & 3) == 0) statsL[pp] = ssum;
    }
    __syncthreads();
    if (active) {
      float S3 = statsL[row * 2 + 0], Q3 = statsL[row * 2 + 1];
      const float invh = 1.0f / 1024.0f;
      float m3 = S3 * invh;
      float i3 = rsqrtf(Q3 * invh - m3 * m3 + 1e-5f);
      float hy = ogate * tanhf((creg - m3) * i3 * ghov + behov);
      unsigned hv = f2bf(hy);
      unsigned lv = f2bf(hy - bf2f(hv));
      unsigned hv2 = (unsigned)__shfl_down((int)hv, 1);
      unsigned lv2 = (unsigned)__shfl_down((int)lv, 1);
      if ((c8 & 1) == 0) {
        size_t i32 = (((size_t)(slot * 2 + layer) * 64 + row) * 1024 + hcol) >> 1;
        AST((unsigned*)p.hpHi + i32, hv | (hv2 << 16));
        AST((unsigned*)p.hpLo + i32, lv | (lv2 << 16));
      }
      size_t yo = ((size_t)t0 * B_ + row) * H_ + hcol;
      p.XYhi[yo] = (unsigned short)hv;
      p.XYlo[yo] = (unsigned short)lv;
    }
    __syncthreads();
    if (tid == 0) atomicAdd(CSET(2, layer) + subj * 16, 1u);
  }

  // ---- span epilogue: persist c-state ----
  p.cst[((size_t)(layer * B_ + row)) * H_ + hcol] = creg;
}

// ---------------------------------------------------------------------------
extern "C" void kernel_launch(void* const* d_in, const int* in_sizes, int n_in,
                              void* d_out, int out_size, void* d_ws, size_t ws_size,
                              hipStream_t stream) {
  const float* x    = (const float*)d_in[0];
  const float* w_ih = (const float*)d_in[1];
  const float* b_ih = (const float*)d_in[2];
  const float* w_hh = (const float*)d_in[3];
  const float* b_hh = (const float*)d_in[4];
  const float* g_ih = (const float*)d_in[5];
  const float* be_ih= (const float*)d_in[6];
  const float* g_hh = (const float*)d_in[7];
  const float* be_hh= (const float*)d_in[8];
  const float* g_ho = (const float*)d_in[9];
  const float* be_ho= (const float*)d_in[10];
  const float* fc_w = (const float*)d_in[11];
  const float* fc_b = (const float*)d_in[12];
  float* out = (float*)d_out;
  (void)ws_size; (void)in_sizes; (void)n_in; (void)out_size;

  // workspace carve-up (~243 MB)
  char* wsb = (char*)d_ws;
  size_t off = 0;
  unsigned short* wihHi  = (unsigned short*)(wsb + off); off += 16777216;
  unsigned short* wihLo  = (unsigned short*)(wsb + off); off += 16777216;
  unsigned short* whhF   = (unsigned short*)(wsb + off); off += 33554432;
  unsigned short* fcHi   = (unsigned short*)(wsb + off); off += 2097152;
  unsigned short* fcLo   = (unsigned short*)(wsb + off); off += 2097152;
  unsigned short* XYhi   = (unsigned short*)(wsb + off); off += 67108864;
  unsigned short* XYlo   = (unsigned short*)(wsb + off); off += 67108864;
  float* P0              = (float*)(wsb + off); off += (size_t)16 * B_ * FH_ * 4;
  float* P1              = (float*)(wsb + off); off += (size_t)16 * B_ * FH_ * 4;
  unsigned short* hpHi   = (unsigned short*)(wsb + off); off += 4194304;  // [16][2][64][1024]
  unsigned short* hpLo   = (unsigned short*)(wsb + off); off += 4194304;
  float* cst             = (float*)(wsb + off); off += 524288;
  float* part1           = (float*)(wsb + off); off += 4194304;  // [16][2][64][4][128]
  float* part2           = (float*)(wsb + off); off += 2097152;  // [16][2][64][2][128]
  unsigned* cnt          = (unsigned*)(wsb + off); off += 3072;  // 3 sets x [2][8x16]

  // --- weight prep ---
  {
    int n4 = 2 * FH_ * D_ / 4;
    cast_split_k<<<(n4 + 255) / 256, 256, 0, stream>>>((const float4*)w_ih, (us4*)wihHi, (us4*)wihLo, n4);
    int nf = H_ * H_ / 4;
    cast_split_k<<<(nf + 255) / 256, 256, 0, stream>>>((const float4*)fc_w, (us4*)fcHi, (us4*)fcLo, nf);
    int nx = T_ * B_ * D_ / 4;
    transpose_split_k<<<nx / 256, 256, 0, stream>>>((const float4*)x, (us4*)XYhi, (us4*)XYlo);
    whh_frag3_k<<<8192, 256, 0, stream>>>(w_hh, whhF);
  }

  // --- state init (graph nodes; re-run each replay) ---
  hipMemsetAsync(hpHi, 0, 8388608, stream);            // hpHi+hpLo contiguous
  hipMemsetAsync(cst, 0, 524288, stream);
  hipMemsetAsync(cnt, 0, 3072, stream);

  hipFuncSetAttribute(reinterpret_cast<const void*>(span_k),
                      hipFuncAttributeMaxDynamicSharedMemorySize, SMEM_TOTAL);

  // --- recurrence: 33 span launches, chunk GEMMs interleaved ---
  SpanP prm;
  prm.whhF = whhF; prm.P0 = P0; prm.P1 = P1;
  prm.hpHi = hpHi; prm.hpLo = hpLo; prm.XYhi = XYhi; prm.XYlo = XYlo;
  prm.cst = cst;
  prm.bhh = b_hh; prm.gih = g_ih; prm.beih = be_ih;
  prm.ghh = g_hh; prm.behh = be_hh; prm.gho = g_ho; prm.beho = be_ho;
  prm.part1 = part1; prm.part2 = part2;
  prm.cnt = cnt;

  for (int c = 0; c < SPANS; ++c) {
    int s = c * NSPAN;
    if (s < T_) {
      gemm3_k<0><<<dim3(FH_ / 128, RCH_ / 128), 256, 0, stream>>>(
          XYhi + (size_t)s * B_ * D_, XYlo + (size_t)s * B_ * D_,
          wihHi, wihLo, b_ih, P0, D_, FH_);
    }
    if (s >= LAG_) {
      gemm3_k<0><<<dim3(FH_ / 128, RCH_ / 128), 256, 0, stream>>>(
          XYhi + (size_t)(s - LAG_) * B_ * D_, XYlo + (size_t)(s - LAG_) * B_ * D_,
          wihHi + (1 << 22), wihLo + (1 << 22), b_ih + FH_, P1, D_, FH_);
    }
    prm.s0 = s;
    span_k<<<256, 512, SMEM_TOTAL, stream>>>(prm);
  }

  // --- final FC: out[b][t][c] = Y1[t*B+b,:]·fc_w[c,:] + fc_b ---
  gemm3_k<1><<<dim3(H_ / 128, (T_ * B_) / 128), 256, 0, stream>>>(
      XYhi, XYlo, fcHi, fcLo, fc_b, out, H_, H_);
}